// Round 1
// baseline (2067.542 us; speedup 1.0000x reference)
//
#include <hip/hip_runtime.h>
#include <math.h>

#define BN_EPS 1e-3f

constexpr int Bn = 4, Hn = 64, Wn = 64, CIN = 512, CI = 128;
constexpr int HWn = Hn * Wn;        // 4096
constexpr int NPIX = Bn * HWn;      // 16384
constexpr int COn = 19;

struct F8 { float4 lo, hi; };

__device__ __forceinline__ F8 f8zero() {
    F8 r; r.lo = make_float4(0.f,0.f,0.f,0.f); r.hi = make_float4(0.f,0.f,0.f,0.f); return r;
}
__device__ __forceinline__ void fma8(F8 &acc, float a, const float4 &wlo, const float4 &whi) {
    acc.lo.x = fmaf(a, wlo.x, acc.lo.x);
    acc.lo.y = fmaf(a, wlo.y, acc.lo.y);
    acc.lo.z = fmaf(a, wlo.z, acc.lo.z);
    acc.lo.w = fmaf(a, wlo.w, acc.lo.w);
    acc.hi.x = fmaf(a, whi.x, acc.hi.x);
    acc.hi.y = fmaf(a, whi.y, acc.hi.y);
    acc.hi.z = fmaf(a, whi.z, acc.hi.z);
    acc.hi.w = fmaf(a, whi.w, acc.hi.w);
}

// ---------------- K1: dual 3x3 conv (x -> feat1, feat2) + BN + ReLU ----------
__global__ __launch_bounds__(256)
void k_conv1(const float* __restrict__ x,
             const float* __restrict__ wA, const float* __restrict__ wB,
             const float* __restrict__ g1, const float* __restrict__ b1,
             const float* __restrict__ m1, const float* __restrict__ v1,
             const float* __restrict__ g2, const float* __restrict__ b2,
             const float* __restrict__ m2, const float* __restrict__ v2,
             float* __restrict__ feat1, float* __restrict__ feat2)
{
    __shared__ __align__(16) float A[34*65];
    __shared__ __align__(16) float W1l[64*128];
    __shared__ __align__(16) float W2l[64*128];
    const int t  = threadIdx.x;
    const int pb = blockIdx.x * 32;
    const int bb = pb / HWn;
    const int hh = (pb % HWn) / Wn;
    const int w0 = pb % Wn;
    const int px = t & 15;
    const int co = (t >> 4) * 8;

    F8 a1a = f8zero(), a1b = f8zero(), a2a = f8zero(), a2b = f8zero();

    for (int dy = 0; dy < 3; ++dy) {
        const int hy = hh + dy - 1;
        if (hy < 0 || hy >= Hn) continue;           // uniform over block
        const float* xrow = x + (size_t)(bb*Hn + hy) * Wn * CIN;
        for (int ch = 0; ch < 8; ++ch) {
            __syncthreads();                         // guard A/W overwrite
            for (int idx = t; idx < 34*64; idx += 256) {
                const int col = idx >> 6, kk = idx & 63;
                const int wx = w0 - 1 + col;
                float val = 0.f;
                if (wx >= 0 && wx < Wn) val = xrow[(size_t)wx*CIN + ch*64 + kk];
                A[col*65 + kk] = val;
            }
            for (int dx = 0; dx < 3; ++dx) {
                if (dx) __syncthreads();
                const int tap = dy*3 + dx;
                const float* w1s = wA + ((size_t)tap*CIN + ch*64) * CI;
                const float* w2s = wB + ((size_t)tap*CIN + ch*64) * CI;
                #pragma unroll
                for (int r = 0; r < 8; ++r) {
                    const int i4 = t + r*256;
                    const int kk = i4 >> 5, c4 = (i4 & 31) * 4;
                    *(float4*)&W1l[kk*128 + c4] = *(const float4*)&w1s[(size_t)kk*CI + c4];
                    *(float4*)&W2l[kk*128 + c4] = *(const float4*)&w2s[(size_t)kk*CI + c4];
                }
                __syncthreads();
                const float* Ar0 = &A[(px + dx)*65];
                const float* Ar1 = &A[(px + 16 + dx)*65];
                #pragma unroll 4
                for (int kk = 0; kk < 64; ++kk) {
                    const float a0 = Ar0[kk], a1 = Ar1[kk];
                    const float4 u0 = *(const float4*)&W1l[kk*128 + co];
                    const float4 u1 = *(const float4*)&W1l[kk*128 + co + 4];
                    const float4 s0 = *(const float4*)&W2l[kk*128 + co];
                    const float4 s1 = *(const float4*)&W2l[kk*128 + co + 4];
                    fma8(a1a, a0, u0, u1);
                    fma8(a1b, a1, u0, u1);
                    fma8(a2a, a0, s0, s1);
                    fma8(a2b, a1, s0, s1);
                }
            }
        }
    }
    const int p0 = pb + px, p1 = p0 + 16;
    const float* f1a = (const float*)&a1a;
    const float* f1b = (const float*)&a1b;
    const float* f2a = (const float*)&a2a;
    const float* f2b = (const float*)&a2b;
    #pragma unroll
    for (int j = 0; j < 8; ++j) {
        const int c = co + j;
        const float s1 = g1[c] * rsqrtf(v1[c] + BN_EPS);
        feat1[(size_t)p0*CI + c] = fmaxf((f1a[j] - m1[c]) * s1 + b1[c], 0.f);
        feat1[(size_t)p1*CI + c] = fmaxf((f1b[j] - m1[c]) * s1 + b1[c], 0.f);
        const float s2 = g2[c] * rsqrtf(v2[c] + BN_EPS);
        feat2[(size_t)p0*CI + c] = fmaxf((f2a[j] - m2[c]) * s2 + b2[c], 0.f);
        feat2[(size_t)p1*CI + c] = fmaxf((f2b[j] - m2[c]) * s2 + b2[c], 0.f);
    }
}

// ---------------- K2a: q,k 1x1 conv ([NPIX,128] x [128,32] + bias) -----------
__global__ __launch_bounds__(256)
void k_qk(const float* __restrict__ feat1,
          const float* __restrict__ wq, const float* __restrict__ bq,
          const float* __restrict__ wk, const float* __restrict__ bk,
          float* __restrict__ qb, float* __restrict__ kb)
{
    __shared__ float Al[64*129];
    __shared__ __align__(16) float Wl[128*32];
    const int t = threadIdx.x;
    const int pb = blockIdx.x * 64;
    for (int idx = t; idx < 64*128; idx += 256) {
        const int p = idx >> 7, ci = idx & 127;
        Al[p*129 + ci] = feat1[(size_t)(pb + p)*CI + ci];
    }
    for (int idx = t; idx < 128*32; idx += 256) {
        const int ci = idx >> 5, c = idx & 31;
        Wl[idx] = (c < 16) ? wq[ci*16 + c] : wk[ci*16 + (c - 16)];
    }
    __syncthreads();
    const int p = t & 63, cg = t >> 6, co = cg * 8;
    F8 acc = f8zero();
    #pragma unroll 8
    for (int ci = 0; ci < 128; ++ci) {
        const float a = Al[p*129 + ci];
        const float4 wlo = *(const float4*)&Wl[ci*32 + co];
        const float4 whi = *(const float4*)&Wl[ci*32 + co + 4];
        fma8(acc, a, wlo, whi);
    }
    const float* af = (const float*)&acc;
    #pragma unroll
    for (int j = 0; j < 8; ++j) {
        const int c = co + j;
        if (c < 16) qb[(size_t)(pb + p)*16 + c]        = af[j] + bq[c];
        else        kb[(size_t)(pb + p)*16 + (c - 16)] = af[j] + bk[c - 16];
    }
}

// ---------------- K2b: v 1x1 conv ([NPIX,128] x [128,128] + bias) ------------
__global__ __launch_bounds__(256)
void k_v(const float* __restrict__ feat1, const float* __restrict__ wv,
         const float* __restrict__ bv, float* __restrict__ vb)
{
    __shared__ float Al[32*129];
    __shared__ __align__(16) float Wl[64*128];
    const int t = threadIdx.x;
    const int pb = blockIdx.x * 32;
    for (int idx = t; idx < 32*128; idx += 256) {
        const int p = idx >> 7, ci = idx & 127;
        Al[p*129 + ci] = feat1[(size_t)(pb + p)*CI + ci];
    }
    const int px = t & 15, co = (t >> 4) * 8;
    F8 acc0 = f8zero(), acc1 = f8zero();
    for (int ch = 0; ch < 2; ++ch) {
        __syncthreads();
        #pragma unroll
        for (int r = 0; r < 8; ++r) {
            const int i4 = t + r*256;
            const int kk = i4 >> 5, c4 = (i4 & 31) * 4;
            *(float4*)&Wl[kk*128 + c4] = *(const float4*)&wv[(size_t)(ch*64 + kk)*CI + c4];
        }
        __syncthreads();
        #pragma unroll 4
        for (int kk = 0; kk < 64; ++kk) {
            const float a0 = Al[px*129 + ch*64 + kk];
            const float a1 = Al[(px+16)*129 + ch*64 + kk];
            const float4 wlo = *(const float4*)&Wl[kk*128 + co];
            const float4 whi = *(const float4*)&Wl[kk*128 + co + 4];
            fma8(acc0, a0, wlo, whi);
            fma8(acc1, a1, wlo, whi);
        }
    }
    const int p0 = pb + px, p1 = p0 + 16;
    const float* a0f = (const float*)&acc0;
    const float* a1f = (const float*)&acc1;
    #pragma unroll
    for (int j = 0; j < 8; ++j) {
        const int c = co + j;
        vb[(size_t)p0*CI + c] = a0f[j] + bv[c];
        vb[(size_t)p1*CI + c] = a1f[j] + bv[c];
    }
}

// ---------------- K3: PAM flash attention + residual -------------------------
__global__ __launch_bounds__(512)
void k_pam(const float* __restrict__ qb, const float* __restrict__ kb,
           const float* __restrict__ vb, const float* __restrict__ feat1,
           const float* __restrict__ gamma, float* __restrict__ sa_feat)
{
    __shared__ __align__(16) float KT[16*64];
    __shared__ __align__(16) float Vt[64*128];
    const int t = threadIdx.x, lane = t & 63, wv_ = t >> 6;
    const int rb = blockIdx.x * 16;
    const int bb = rb / HWn;
    const size_t r0 = (size_t)rb + wv_*2, r1 = r0 + 1;
    const float q0l = (lane < 16) ? qb[r0*16 + lane] : 0.f;
    const float q1l = (lane < 16) ? qb[r1*16 + lane] : 0.f;
    float q0r[16], q1r[16];
    #pragma unroll
    for (int c = 0; c < 16; ++c) { q0r[c] = __shfl(q0l, c); q1r[c] = __shfl(q1l, c); }

    float m0 = -1e30f, m1 = -1e30f, s0 = 0.f, s1 = 0.f;
    float2 o0 = make_float2(0.f,0.f), o1 = make_float2(0.f,0.f);
    const size_t jbase = (size_t)bb * HWn;

    for (int j0 = 0; j0 < HWn; j0 += 64) {
        __syncthreads();
        if (t < 256) {
            const int j = t >> 2, c4 = (t & 3) * 4;
            const float4 kv = *(const float4*)&kb[(jbase + j0 + j)*16 + c4];
            KT[(c4+0)*64 + j] = kv.x;
            KT[(c4+1)*64 + j] = kv.y;
            KT[(c4+2)*64 + j] = kv.z;
            KT[(c4+3)*64 + j] = kv.w;
        }
        #pragma unroll
        for (int r = 0; r < 4; ++r) {
            const int i4 = t + r*512;
            const int j = i4 >> 5, c4 = (i4 & 31) * 4;
            *(float4*)&Vt[j*128 + c4] = *(const float4*)&vb[(jbase + j0 + j)*CI + c4];
        }
        __syncthreads();
        float e0 = 0.f, e1 = 0.f;
        #pragma unroll
        for (int c = 0; c < 16; ++c) {
            const float kc = KT[c*64 + lane];
            e0 = fmaf(q0r[c], kc, e0);
            e1 = fmaf(q1r[c], kc, e1);
        }
        float t0 = e0, t1 = e1;
        #pragma unroll
        for (int off = 32; off > 0; off >>= 1) {
            t0 = fmaxf(t0, __shfl_xor(t0, off));
            t1 = fmaxf(t1, __shfl_xor(t1, off));
        }
        const float mn0 = fmaxf(m0, t0), mn1 = fmaxf(m1, t1);
        const float al0 = __expf(m0 - mn0), al1 = __expf(m1 - mn1);
        const float p0 = __expf(e0 - mn0), p1 = __expf(e1 - mn1);
        s0 = s0*al0 + p0; s1 = s1*al1 + p1;
        o0.x *= al0; o0.y *= al0; o1.x *= al1; o1.y *= al1;
        m0 = mn0; m1 = mn1;
        #pragma unroll 8
        for (int jj = 0; jj < 64; ++jj) {
            const float pj0 = __shfl(p0, jj);
            const float pj1 = __shfl(p1, jj);
            const float2 vvv = *(const float2*)&Vt[jj*128 + lane*2];
            o0.x = fmaf(pj0, vvv.x, o0.x);
            o0.y = fmaf(pj0, vvv.y, o0.y);
            o1.x = fmaf(pj1, vvv.x, o1.x);
            o1.y = fmaf(pj1, vvv.y, o1.y);
        }
    }
    #pragma unroll
    for (int off = 32; off > 0; off >>= 1) {
        s0 += __shfl_xor(s0, off);
        s1 += __shfl_xor(s1, off);
    }
    const float inv0 = 1.f/s0, inv1 = 1.f/s1;
    const float g = gamma[0];
    const int c0 = lane*2;
    const float2 f0 = *(const float2*)&feat1[r0*CI + c0];
    const float2 f1 = *(const float2*)&feat1[r1*CI + c0];
    float2 w0, w1;
    w0.x = g*(o0.x*inv0) + f0.x;  w0.y = g*(o0.y*inv0) + f0.y;
    w1.x = g*(o1.x*inv1) + f1.x;  w1.y = g*(o1.y*inv1) + f1.y;
    *(float2*)&sa_feat[r0*CI + c0] = w0;
    *(float2*)&sa_feat[r1*CI + c0] = w1;
}

// ---------------- K4a: CAM energy = X^T X (per batch, 32x32 tiles) ----------
__global__ __launch_bounds__(256)
void k_cam_energy(const float* __restrict__ feat2, float* __restrict__ energy)
{
    __shared__ float Xc[64*33];
    __shared__ float Xd[64*33];
    const int t = threadIdx.x;
    const int tile = blockIdx.x;            // 0..15
    const int bb = blockIdx.y;
    const int c0 = (tile & 3) * 32, d0 = (tile >> 2) * 32;
    const int tc = t & 31, dg = t >> 5;     // dg 0..7
    float acc[4] = {0.f,0.f,0.f,0.f};
    const size_t base = (size_t)bb * HWn;
    for (int n0 = 0; n0 < HWn; n0 += 64) {
        __syncthreads();
        for (int idx = t; idx < 64*32; idx += 256) {
            const int n = idx >> 5, col = idx & 31;
            Xc[n*33 + col] = feat2[(base + n0 + n)*CI + c0 + col];
            Xd[n*33 + col] = feat2[(base + n0 + n)*CI + d0 + col];
        }
        __syncthreads();
        #pragma unroll 4
        for (int n = 0; n < 64; ++n) {
            const float a = Xc[n*33 + tc];
            #pragma unroll
            for (int i = 0; i < 4; ++i)
                acc[i] = fmaf(a, Xd[n*33 + dg*4 + i], acc[i]);
        }
    }
    const int c = c0 + tc;
    #pragma unroll
    for (int i = 0; i < 4; ++i)
        energy[((size_t)bb*CI + c)*CI + d0 + dg*4 + i] = acc[i];
}

// ---------------- K4b: CAM softmax (max-subtract variant, per row) ----------
__global__ __launch_bounds__(64)
void k_cam_softmax(const float* __restrict__ energy, float* __restrict__ att)
{
    const int lane = threadIdx.x;
    const size_t row = blockIdx.x;          // 0..511  (= b*128 + c)
    const float2 e = *(const float2*)&energy[row*CI + lane*2];
    float M = fmaxf(e.x, e.y);
    #pragma unroll
    for (int off = 32; off > 0; off >>= 1) M = fmaxf(M, __shfl_xor(M, off));
    const float en0 = M - e.x, en1 = M - e.y;
    float mx = fmaxf(en0, en1);
    #pragma unroll
    for (int off = 32; off > 0; off >>= 1) mx = fmaxf(mx, __shfl_xor(mx, off));
    const float p0 = __expf(en0 - mx), p1 = __expf(en1 - mx);
    float s = p0 + p1;
    #pragma unroll
    for (int off = 32; off > 0; off >>= 1) s += __shfl_xor(s, off);
    const float inv = 1.f / s;
    float2 o; o.x = p0*inv; o.y = p1*inv;
    *(float2*)&att[row*CI + lane*2] = o;
}

// ---------------- K4c: CAM apply: sc = g*(X att^T) + X ----------------------
__global__ __launch_bounds__(256)
void k_cam_apply(const float* __restrict__ feat2, const float* __restrict__ att,
                 const float* __restrict__ gamma, float* __restrict__ sc_feat)
{
    __shared__ float Xl[64*129];
    __shared__ __align__(16) float aT[128*64];
    const int t = threadIdx.x;
    const int pb = blockIdx.x * 64;
    const int bb = pb / HWn;
    const int ch = blockIdx.y * 64;
    for (int idx = t; idx < 64*128; idx += 256) {
        const int p = idx >> 7, ci = idx & 127;
        Xl[p*129 + ci] = feat2[(size_t)(pb + p)*CI + ci];
    }
    for (int idx = t; idx < 128*64; idx += 256) {
        const int d = idx >> 6, cc = idx & 63;
        aT[d*64 + cc] = att[((size_t)bb*CI + ch + cc)*CI + d];
    }
    __syncthreads();
    const int px = t & 63, cg = t >> 6;
    F8 accA = f8zero(), accB = f8zero();
    #pragma unroll 4
    for (int d = 0; d < 128; ++d) {
        const float xv = Xl[px*129 + d];
        const float* ap = &aT[d*64 + cg*16];
        const float4 a0 = *(const float4*)&ap[0];
        const float4 a1 = *(const float4*)&ap[4];
        const float4 a2 = *(const float4*)&ap[8];
        const float4 a3 = *(const float4*)&ap[12];
        fma8(accA, xv, a0, a1);
        fma8(accB, xv, a2, a3);
    }
    const float g = gamma[0];
    const float* fa = (const float*)&accA;
    const float* fb = (const float*)&accB;
    #pragma unroll
    for (int j = 0; j < 8; ++j) {
        const int cA = ch + cg*16 + j;
        const int cB = cA + 8;
        sc_feat[(size_t)(pb + px)*CI + cA] = g*fa[j] + Xl[px*129 + cA];
        sc_feat[(size_t)(pb + px)*CI + cB] = g*fb[j] + Xl[px*129 + cB];
    }
}

// ---------------- K6: dual 3x3 conv + BN + ReLU + sum -----------------------
__global__ __launch_bounds__(256)
void k_conv2(const float* __restrict__ inA, const float* __restrict__ inB,
             const float* __restrict__ wA, const float* __restrict__ wB,
             const float* __restrict__ g3, const float* __restrict__ b3,
             const float* __restrict__ m3, const float* __restrict__ v3,
             const float* __restrict__ g4, const float* __restrict__ b4,
             const float* __restrict__ m4, const float* __restrict__ v4,
             float* __restrict__ fsum)
{
    __shared__ float A1[34*33];
    __shared__ float A2[34*33];
    __shared__ __align__(16) float W1l[32*128];
    __shared__ __align__(16) float W2l[32*128];
    const int t = threadIdx.x;
    const int pb = blockIdx.x * 32;
    const int bb = pb / HWn, hh = (pb % HWn)/Wn, w0 = pb % Wn;
    const int px = t & 15, co = (t >> 4) * 8;
    F8 a1a = f8zero(), a1b = f8zero(), a2a = f8zero(), a2b = f8zero();

    for (int dy = 0; dy < 3; ++dy) {
        const int hy = hh + dy - 1;
        if (hy < 0 || hy >= Hn) continue;
        const size_t rbase = (size_t)(bb*Hn + hy) * Wn;
        for (int ch = 0; ch < 4; ++ch) {
            __syncthreads();
            for (int idx = t; idx < 34*32; idx += 256) {
                const int col = idx >> 5, kk = idx & 31;
                const int wx = w0 - 1 + col;
                float u = 0.f, s = 0.f;
                if (wx >= 0 && wx < Wn) {
                    const size_t gi = (rbase + wx)*CI + ch*32 + kk;
                    u = inA[gi]; s = inB[gi];
                }
                A1[col*33 + kk] = u;
                A2[col*33 + kk] = s;
            }
            for (int dx = 0; dx < 3; ++dx) {
                if (dx) __syncthreads();
                const int tap = dy*3 + dx;
                const float* w1s = wA + ((size_t)tap*CI + ch*32) * CI;
                const float* w2s = wB + ((size_t)tap*CI + ch*32) * CI;
                #pragma unroll
                for (int r = 0; r < 4; ++r) {
                    const int i4 = t + r*256;
                    const int kk = i4 >> 5, c4 = (i4 & 31) * 4;
                    *(float4*)&W1l[kk*128 + c4] = *(const float4*)&w1s[(size_t)kk*CI + c4];
                    *(float4*)&W2l[kk*128 + c4] = *(const float4*)&w2s[(size_t)kk*CI + c4];
                }
                __syncthreads();
                const float* A1r0 = &A1[(px + dx)*33];
                const float* A1r1 = &A1[(px + 16 + dx)*33];
                const float* A2r0 = &A2[(px + dx)*33];
                const float* A2r1 = &A2[(px + 16 + dx)*33];
                #pragma unroll 4
                for (int kk = 0; kk < 32; ++kk) {
                    const float x1a = A1r0[kk], x1b = A1r1[kk];
                    const float x2a = A2r0[kk], x2b = A2r1[kk];
                    const float4 u0 = *(const float4*)&W1l[kk*128 + co];
                    const float4 u1 = *(const float4*)&W1l[kk*128 + co + 4];
                    const float4 s0 = *(const float4*)&W2l[kk*128 + co];
                    const float4 s1 = *(const float4*)&W2l[kk*128 + co + 4];
                    fma8(a1a, x1a, u0, u1);
                    fma8(a1b, x1b, u0, u1);
                    fma8(a2a, x2a, s0, s1);
                    fma8(a2b, x2b, s0, s1);
                }
            }
        }
    }
    const int p0 = pb + px, p1 = p0 + 16;
    const float* f1a = (const float*)&a1a;
    const float* f1b = (const float*)&a1b;
    const float* f2a = (const float*)&a2a;
    const float* f2b = (const float*)&a2b;
    #pragma unroll
    for (int j = 0; j < 8; ++j) {
        const int c = co + j;
        const float s3 = g3[c] * rsqrtf(v3[c] + BN_EPS);
        const float s4 = g4[c] * rsqrtf(v4[c] + BN_EPS);
        const float o1a = fmaxf((f1a[j] - m3[c])*s3 + b3[c], 0.f);
        const float o1b = fmaxf((f1b[j] - m3[c])*s3 + b3[c], 0.f);
        const float o2a = fmaxf((f2a[j] - m4[c])*s4 + b4[c], 0.f);
        const float o2b = fmaxf((f2b[j] - m4[c])*s4 + b4[c], 0.f);
        fsum[(size_t)p0*CI + c] = o1a + o2a;
        fsum[(size_t)p1*CI + c] = o1b + o2b;
    }
}

// ---------------- K7: final 1x1 conv -> out ---------------------------------
__global__ __launch_bounds__(256)
void k_final(const float* __restrict__ fsum, const float* __restrict__ w8,
             float* __restrict__ out)
{
    __shared__ float Xl[64*129];
    __shared__ float w8l[128*COn];
    const int t = threadIdx.x;
    const int pb = blockIdx.x * 64;
    for (int idx = t; idx < 64*128; idx += 256) {
        const int p = idx >> 7, ci = idx & 127;
        Xl[p*129 + ci] = fsum[(size_t)(pb + p)*CI + ci];
    }
    for (int idx = t; idx < 128*COn; idx += 256) w8l[idx] = w8[idx];
    __syncthreads();
    for (int idx = t; idx < 64*COn; idx += 256) {
        const int p = idx / COn, co = idx - p*COn;
        float acc = 0.f;
        #pragma unroll 8
        for (int ci = 0; ci < 128; ++ci)
            acc = fmaf(Xl[p*129 + ci], w8l[ci*COn + co], acc);
        out[(size_t)(pb + p)*COn + co] = acc;
    }
}

extern "C" void kernel_launch(void* const* d_in, const int* in_sizes, int n_in,
                              void* d_out, int out_size, void* d_ws, size_t ws_size,
                              hipStream_t stream)
{
    const float* x    = (const float*)d_in[0];
    const float* w5a  = (const float*)d_in[1];
    const float* w5c  = (const float*)d_in[2];
    const float* wq   = (const float*)d_in[3];
    const float* bq   = (const float*)d_in[4];
    const float* wk   = (const float*)d_in[5];
    const float* bk   = (const float*)d_in[6];
    const float* wv   = (const float*)d_in[7];
    const float* bv   = (const float*)d_in[8];
    const float* pgam = (const float*)d_in[9];
    const float* cgam = (const float*)d_in[10];
    const float* w51  = (const float*)d_in[11];
    const float* w52  = (const float*)d_in[12];
    const float* w8   = (const float*)d_in[13];
    const float* bn1g = (const float*)d_in[14];
    const float* bn1b = (const float*)d_in[15];
    const float* bn1m = (const float*)d_in[16];
    const float* bn1v = (const float*)d_in[17];
    const float* bn2g = (const float*)d_in[18];
    const float* bn2b = (const float*)d_in[19];
    const float* bn2m = (const float*)d_in[20];
    const float* bn2v = (const float*)d_in[21];
    const float* bn3g = (const float*)d_in[22];
    const float* bn3b = (const float*)d_in[23];
    const float* bn3m = (const float*)d_in[24];
    const float* bn3v = (const float*)d_in[25];
    const float* bn4g = (const float*)d_in[26];
    const float* bn4b = (const float*)d_in[27];
    const float* bn4m = (const float*)d_in[28];
    const float* bn4v = (const float*)d_in[29];

    float* ws = (float*)d_ws;
    float* feat1  = ws;                  // 2097152 floats (reused as feat_sum)
    float* feat2  = ws + 2097152;        // 2097152
    float* qb     = ws + 4194304;        // 262144
    float* kb     = ws + 4456448;        // 262144
    float* vb     = ws + 4718592;        // 2097152
    float* saf    = ws + 6815744;        // 2097152
    float* scf    = ws + 8912896;        // 2097152
    float* energy = ws + 11010048;       // 65536
    float* att    = ws + 11075584;       // 65536
    float* fsum   = feat1;               // alias: feat1 dead after k_pam
    float* out    = (float*)d_out;

    k_conv1<<<dim3(NPIX/32), 256, 0, stream>>>(x, w5a, w5c,
        bn1g, bn1b, bn1m, bn1v, bn2g, bn2b, bn2m, bn2v, feat1, feat2);
    k_qk<<<dim3(NPIX/64), 256, 0, stream>>>(feat1, wq, bq, wk, bk, qb, kb);
    k_v<<<dim3(NPIX/32), 256, 0, stream>>>(feat1, wv, bv, vb);
    k_pam<<<dim3(NPIX/16), 512, 0, stream>>>(qb, kb, vb, feat1, pgam, saf);
    k_cam_energy<<<dim3(16, Bn), 256, 0, stream>>>(feat2, energy);
    k_cam_softmax<<<dim3(Bn*CI), 64, 0, stream>>>(energy, att);
    k_cam_apply<<<dim3(NPIX/64, 2), 256, 0, stream>>>(feat2, att, cgam, scf);
    k_conv2<<<dim3(NPIX/32), 256, 0, stream>>>(saf, scf, w51, w52,
        bn3g, bn3b, bn3m, bn3v, bn4g, bn4b, bn4m, bn4v, fsum);
    k_final<<<dim3(NPIX/64), 256, 0, stream>>>(fsum, w8, out);
}

// Round 3
// 1097.590 us; speedup vs baseline: 1.8837x; 1.8837x over previous
//
#include <hip/hip_runtime.h>
#include <hip/hip_bf16.h>
#include <math.h>

#define BN_EPS 1e-3f

constexpr int Bn = 4, Hn = 64, Wn = 64, CIN = 512, CI = 128;
constexpr int HWn = Hn * Wn;        // 4096
constexpr int NPIX = Bn * HWn;      // 16384
constexpr int COn = 19;

struct F8 { float4 lo, hi; };

__device__ __forceinline__ F8 f8zero() {
    F8 r; r.lo = make_float4(0.f,0.f,0.f,0.f); r.hi = make_float4(0.f,0.f,0.f,0.f); return r;
}
__device__ __forceinline__ void fma8(F8 &acc, float a, const float4 &wlo, const float4 &whi) {
    acc.lo.x = fmaf(a, wlo.x, acc.lo.x);
    acc.lo.y = fmaf(a, wlo.y, acc.lo.y);
    acc.lo.z = fmaf(a, wlo.z, acc.lo.z);
    acc.lo.w = fmaf(a, wlo.w, acc.lo.w);
    acc.hi.x = fmaf(a, whi.x, acc.hi.x);
    acc.hi.y = fmaf(a, whi.y, acc.hi.y);
    acc.hi.z = fmaf(a, whi.z, acc.hi.z);
    acc.hi.w = fmaf(a, whi.w, acc.hi.w);
}

// ---- MFMA helpers -----------------------------------------------------------
typedef __attribute__((ext_vector_type(8)))  short short8;   // 8 bf16 in 4 VGPRs
typedef __attribute__((ext_vector_type(16))) float f32x16;

__device__ __forceinline__ f32x16 f16z() {
    f32x16 z;
    #pragma unroll
    for (int i = 0; i < 16; ++i) z[i] = 0.f;
    return z;
}
// fp32 -> bf16 (RNE), pure integer ops — no asm, no HIP-type raw access
__device__ __forceinline__ unsigned f2b(float f) {
    union { float f; unsigned u; } c; c.f = f;
    return (c.u + 0x7FFFu + ((c.u >> 16) & 1u)) >> 16;
}
__device__ __forceinline__ unsigned pack2(float lo, float hi) {
    return (f2b(hi) << 16) | f2b(lo);
}

// ---------------- K1: dual 3x3 conv (x -> feat1, feat2) + BN + ReLU ----------
__global__ __launch_bounds__(256)
void k_conv1(const float* __restrict__ x,
             const float* __restrict__ wA, const float* __restrict__ wB,
             const float* __restrict__ g1, const float* __restrict__ b1,
             const float* __restrict__ m1, const float* __restrict__ v1,
             const float* __restrict__ g2, const float* __restrict__ b2,
             const float* __restrict__ m2, const float* __restrict__ v2,
             float* __restrict__ feat1, float* __restrict__ feat2)
{
    __shared__ __align__(16) float A[34*65];
    __shared__ __align__(16) float W1l[64*128];
    __shared__ __align__(16) float W2l[64*128];
    const int t  = threadIdx.x;
    const int pb = blockIdx.x * 32;
    const int bb = pb / HWn;
    const int hh = (pb % HWn) / Wn;
    const int w0 = pb % Wn;
    const int px = t & 15;
    const int co = (t >> 4) * 8;

    F8 a1a = f8zero(), a1b = f8zero(), a2a = f8zero(), a2b = f8zero();

    for (int dy = 0; dy < 3; ++dy) {
        const int hy = hh + dy - 1;
        if (hy < 0 || hy >= Hn) continue;           // uniform over block
        const float* xrow = x + (size_t)(bb*Hn + hy) * Wn * CIN;
        for (int ch = 0; ch < 8; ++ch) {
            __syncthreads();                         // guard A/W overwrite
            for (int idx = t; idx < 34*64; idx += 256) {
                const int col = idx >> 6, kk = idx & 63;
                const int wx = w0 - 1 + col;
                float val = 0.f;
                if (wx >= 0 && wx < Wn) val = xrow[(size_t)wx*CIN + ch*64 + kk];
                A[col*65 + kk] = val;
            }
            for (int dx = 0; dx < 3; ++dx) {
                if (dx) __syncthreads();
                const int tap = dy*3 + dx;
                const float* w1s = wA + ((size_t)tap*CIN + ch*64) * CI;
                const float* w2s = wB + ((size_t)tap*CIN + ch*64) * CI;
                #pragma unroll
                for (int r = 0; r < 8; ++r) {
                    const int i4 = t + r*256;
                    const int kk = i4 >> 5, c4 = (i4 & 31) * 4;
                    *(float4*)&W1l[kk*128 + c4] = *(const float4*)&w1s[(size_t)kk*CI + c4];
                    *(float4*)&W2l[kk*128 + c4] = *(const float4*)&w2s[(size_t)kk*CI + c4];
                }
                __syncthreads();
                const float* Ar0 = &A[(px + dx)*65];
                const float* Ar1 = &A[(px + 16 + dx)*65];
                #pragma unroll 4
                for (int kk = 0; kk < 64; ++kk) {
                    const float a0 = Ar0[kk], a1 = Ar1[kk];
                    const float4 u0 = *(const float4*)&W1l[kk*128 + co];
                    const float4 u1 = *(const float4*)&W1l[kk*128 + co + 4];
                    const float4 s0 = *(const float4*)&W2l[kk*128 + co];
                    const float4 s1 = *(const float4*)&W2l[kk*128 + co + 4];
                    fma8(a1a, a0, u0, u1);
                    fma8(a1b, a1, u0, u1);
                    fma8(a2a, a0, s0, s1);
                    fma8(a2b, a1, s0, s1);
                }
            }
        }
    }
    const int p0 = pb + px, p1 = p0 + 16;
    const float* f1a = (const float*)&a1a;
    const float* f1b = (const float*)&a1b;
    const float* f2a = (const float*)&a2a;
    const float* f2b = (const float*)&a2b;
    #pragma unroll
    for (int j = 0; j < 8; ++j) {
        const int c = co + j;
        const float s1 = g1[c] * rsqrtf(v1[c] + BN_EPS);
        feat1[(size_t)p0*CI + c] = fmaxf((f1a[j] - m1[c]) * s1 + b1[c], 0.f);
        feat1[(size_t)p1*CI + c] = fmaxf((f1b[j] - m1[c]) * s1 + b1[c], 0.f);
        const float s2 = g2[c] * rsqrtf(v2[c] + BN_EPS);
        feat2[(size_t)p0*CI + c] = fmaxf((f2a[j] - m2[c]) * s2 + b2[c], 0.f);
        feat2[(size_t)p1*CI + c] = fmaxf((f2b[j] - m2[c]) * s2 + b2[c], 0.f);
    }
}

// ---------------- K2a: q,k 1x1 conv -> bf16 [NPIX][16] each ------------------
__global__ __launch_bounds__(256)
void k_qk(const float* __restrict__ feat1,
          const float* __restrict__ wq, const float* __restrict__ bq,
          const float* __restrict__ wk, const float* __restrict__ bk,
          __hip_bfloat16* __restrict__ qb, __hip_bfloat16* __restrict__ kb)
{
    __shared__ float Al[64*129];
    __shared__ __align__(16) float Wl[128*32];
    const int t = threadIdx.x;
    const int pb = blockIdx.x * 64;
    for (int idx = t; idx < 64*128; idx += 256) {
        const int p = idx >> 7, ci = idx & 127;
        Al[p*129 + ci] = feat1[(size_t)(pb + p)*CI + ci];
    }
    for (int idx = t; idx < 128*32; idx += 256) {
        const int ci = idx >> 5, c = idx & 31;
        Wl[idx] = (c < 16) ? wq[ci*16 + c] : wk[ci*16 + (c - 16)];
    }
    __syncthreads();
    const int p = t & 63, cg = t >> 6, co = cg * 8;
    F8 acc = f8zero();
    #pragma unroll 8
    for (int ci = 0; ci < 128; ++ci) {
        const float a = Al[p*129 + ci];
        const float4 wlo = *(const float4*)&Wl[ci*32 + co];
        const float4 whi = *(const float4*)&Wl[ci*32 + co + 4];
        fma8(acc, a, wlo, whi);
    }
    const float* af = (const float*)&acc;
    #pragma unroll
    for (int j = 0; j < 8; ++j) {
        const int c = co + j;
        if (c < 16) qb[(size_t)(pb + p)*16 + c]        = __float2bfloat16(af[j] + bq[c]);
        else        kb[(size_t)(pb + p)*16 + (c - 16)] = __float2bfloat16(af[j] + bk[c - 16]);
    }
}

// ---------------- K2b: v 1x1 conv -> bf16 TRANSPOSED [b][c][pix] -------------
__global__ __launch_bounds__(256)
void k_v(const float* __restrict__ feat1, const float* __restrict__ wv,
         const float* __restrict__ bv, __hip_bfloat16* __restrict__ vbT)
{
    __shared__ float Al[32*129];
    __shared__ __align__(16) float Wl[64*128];
    const int t = threadIdx.x;
    const int pb = blockIdx.x * 32;
    for (int idx = t; idx < 32*128; idx += 256) {
        const int p = idx >> 7, ci = idx & 127;
        Al[p*129 + ci] = feat1[(size_t)(pb + p)*CI + ci];
    }
    const int px = t & 15, co = (t >> 4) * 8;
    F8 acc0 = f8zero(), acc1 = f8zero();
    for (int ch = 0; ch < 2; ++ch) {
        __syncthreads();
        #pragma unroll
        for (int r = 0; r < 8; ++r) {
            const int i4 = t + r*256;
            const int kk = i4 >> 5, c4 = (i4 & 31) * 4;
            *(float4*)&Wl[kk*128 + c4] = *(const float4*)&wv[(size_t)(ch*64 + kk)*CI + c4];
        }
        __syncthreads();
        #pragma unroll 4
        for (int kk = 0; kk < 64; ++kk) {
            const float a0 = Al[px*129 + ch*64 + kk];
            const float a1 = Al[(px+16)*129 + ch*64 + kk];
            const float4 wlo = *(const float4*)&Wl[kk*128 + co];
            const float4 whi = *(const float4*)&Wl[kk*128 + co + 4];
            fma8(acc0, a0, wlo, whi);
            fma8(acc1, a1, wlo, whi);
        }
    }
    const int p0 = pb + px;
    const int bb = p0 / HWn, pin0 = p0 % HWn;   // p0+16 stays in same batch
    const float* a0f = (const float*)&acc0;
    const float* a1f = (const float*)&acc1;
    #pragma unroll
    for (int j = 0; j < 8; ++j) {
        const int c = co + j;
        const size_t rowb = ((size_t)bb*CI + c) * HWn;
        vbT[rowb + pin0]      = __float2bfloat16(a0f[j] + bv[c]);
        vbT[rowb + pin0 + 16] = __float2bfloat16(a1f[j] + bv[c]);
    }
}

// ---------------- K3: PAM flash attention via MFMA ---------------------------
// One wave per 32 query rows. Swapped QK^T: E^T = mfma(A=K, B=Q^T) so the
// C/D column index (lane&31) is the q row -> softmax state is lane-local
// (q row split across lanes l and l+32, reconciled by shfl_xor(32)).
// P transition goes through LDS with EXPLICIT key labels derived from the
// HW-verified C/D map (row=(r&3)+8*(r>>2)+4h). The PV B-fragment is then
// read back by each lane for the key-slice its B-slot claims; any error in
// the true A/B k-grouping cancels identically between the V-fragment and
// P-fragment loads (same assumed map on both operands of the dot product).
__global__ __launch_bounds__(64)
void k_pam(const __hip_bfloat16* __restrict__ qb, const __hip_bfloat16* __restrict__ kb,
           const __hip_bfloat16* __restrict__ vbT, const float* __restrict__ feat1,
           const float* __restrict__ gamma, float* __restrict__ saf)
{
    __shared__ unsigned Ppk[32*32];   // [key-pair 0..31][q 0..31], bf16x2 packed
    const int l   = threadIdx.x;
    const int lo5 = l & 31, h = l >> 5;
    const int q0  = blockIdx.x * 32;
    const int bb  = q0 / HWn;
    const size_t jb = (size_t)bb * HWn;
    const __hip_bfloat16* vbB = vbT + (size_t)bb * CI * HWn;

    // Q fragment (B-operand of E^T): lane holds Q[q0+lo5][8h..8h+7]
    const short8 qfrag = *(const short8*)&qb[(size_t)(q0 + lo5)*16 + 8*h];
    const f32x16 zro = f16z();

    f32x16 o[4];
    #pragma unroll
    for (int cb = 0; cb < 4; ++cb) o[cb] = f16z();

    float m_run = -1e30f, s_run = 0.f;

    for (int k0 = 0; k0 < HWn; k0 += 64) {
        // K fragments for two 32-key tiles: lane holds K[k0+t*32+lo5][8h..+7]
        const short8 kf0 = *(const short8*)&kb[(jb + k0 +      lo5)*16 + 8*h];
        const short8 kf1 = *(const short8*)&kb[(jb + k0 + 32 + lo5)*16 + 8*h];
        // V^T fragments: lane holds V^T[cb*32+lo5][k0+s*16+8h .. +7]
        short8 vf[4][4];
        #pragma unroll
        for (int s = 0; s < 4; ++s)
            #pragma unroll
            for (int cb = 0; cb < 4; ++cb)
                vf[s][cb] = *(const short8*)&vbB[((size_t)(cb*32 + lo5))*HWn + k0 + s*16 + 8*h];

        f32x16 e0 = __builtin_amdgcn_mfma_f32_32x32x16_bf16(kf0, qfrag, zro, 0, 0, 0);
        f32x16 e1 = __builtin_amdgcn_mfma_f32_32x32x16_bf16(kf1, qfrag, zro, 0, 0, 0);

        // tile max for this lane's q row (32 keys here + partner's 32)
        float mt = fmaxf(e0[0], e1[0]);
        #pragma unroll
        for (int r = 1; r < 16; ++r) mt = fmaxf(mt, fmaxf(e0[r], e1[r]));
        mt = fmaxf(mt, __shfl_xor(mt, 32));

        // defer-max (T13): only rescale when the max grew materially
        if (__any(mt > m_run + 8.f)) {
            const float mnew = fmaxf(m_run, mt);
            const float sc = __expf(m_run - mnew);
            s_run *= sc;
            #pragma unroll
            for (int cb = 0; cb < 4; ++cb)
                #pragma unroll
                for (int r = 0; r < 16; ++r) o[cb][r] *= sc;
            m_run = mnew;
        }

        // p = exp(e - m), accumulate lane-partial denominator
        #pragma unroll
        for (int r = 0; r < 16; ++r) {
            e0[r] = __expf(e0[r] - m_run);
            e1[r] = __expf(e1[r] - m_run);
        }
        float ss = 0.f;
        #pragma unroll
        for (int r = 0; r < 16; ++r) ss += e0[r] + e1[r];
        s_run += ss;

        // Store P with explicit key labels from the verified C/D map.
        // Even r: keys (crow, crow+1) form an aligned pair; pair idx = crow/2.
        #pragma unroll
        for (int r = 0; r < 16; r += 2) {
            const int pidx = ((r & 3) >> 1) + 4*(r >> 2) + 2*h;
            Ppk[pidx*32 + lo5]        = pack2(e0[r], e0[r+1]);
            Ppk[(16 + pidx)*32 + lo5] = pack2(e1[r], e1[r+1]);
        }
        // Read back the 4 pairs this lane's B-slot claims (keys 8h..8h+7 of
        // each 16-key slice) and run the PV MFMAs.
        #pragma unroll
        for (int s = 0; s < 4; ++s) {
            union { unsigned u[4]; short8 s8; } P;
            #pragma unroll
            for (int w = 0; w < 4; ++w)
                P.u[w] = Ppk[(s*8 + 4*h + w)*32 + lo5];
            #pragma unroll
            for (int cb = 0; cb < 4; ++cb)
                o[cb] = __builtin_amdgcn_mfma_f32_32x32x16_bf16(vf[s][cb], P.s8, o[cb], 0, 0, 0);
        }
    }

    const float s_tot = s_run + __shfl_xor(s_run, 32);
    const float inv = 1.f / s_tot;
    const float g = gamma[0];
    const size_t q = (size_t)q0 + lo5;
    #pragma unroll
    for (int cb = 0; cb < 4; ++cb)
        #pragma unroll
        for (int r = 0; r < 16; ++r) {
            const int c = cb*32 + (r & 3) + 8*(r >> 2) + 4*h;
            const size_t idx = q*CI + c;
            saf[idx] = g*(o[cb][r]*inv) + feat1[idx];
        }
}

// ---------------- K4a: CAM energy = X^T X (per batch, 32x32 tiles) ----------
__global__ __launch_bounds__(256)
void k_cam_energy(const float* __restrict__ feat2, float* __restrict__ energy)
{
    __shared__ float Xc[64*33];
    __shared__ float Xd[64*33];
    const int t = threadIdx.x;
    const int tile = blockIdx.x;            // 0..15
    const int bb = blockIdx.y;
    const int c0 = (tile & 3) * 32, d0 = (tile >> 2) * 32;
    const int tc = t & 31, dg = t >> 5;     // dg 0..7
    float acc[4] = {0.f,0.f,0.f,0.f};
    const size_t base = (size_t)bb * HWn;
    for (int n0 = 0; n0 < HWn; n0 += 64) {
        __syncthreads();
        for (int idx = t; idx < 64*32; idx += 256) {
            const int n = idx >> 5, col = idx & 31;
            Xc[n*33 + col] = feat2[(base + n0 + n)*CI + c0 + col];
            Xd[n*33 + col] = feat2[(base + n0 + n)*CI + d0 + col];
        }
        __syncthreads();
        #pragma unroll 4
        for (int n = 0; n < 64; ++n) {
            const float a = Xc[n*33 + tc];
            #pragma unroll
            for (int i = 0; i < 4; ++i)
                acc[i] = fmaf(a, Xd[n*33 + dg*4 + i], acc[i]);
        }
    }
    const int c = c0 + tc;
    #pragma unroll
    for (int i = 0; i < 4; ++i)
        energy[((size_t)bb*CI + c)*CI + d0 + dg*4 + i] = acc[i];
}

// ---------------- K4b: CAM softmax (max-subtract variant, per row) ----------
__global__ __launch_bounds__(64)
void k_cam_softmax(const float* __restrict__ energy, float* __restrict__ att)
{
    const int lane = threadIdx.x;
    const size_t row = blockIdx.x;          // 0..511  (= b*128 + c)
    const float2 e = *(const float2*)&energy[row*CI + lane*2];
    float M = fmaxf(e.x, e.y);
    #pragma unroll
    for (int off = 32; off > 0; off >>= 1) M = fmaxf(M, __shfl_xor(M, off));
    const float en0 = M - e.x, en1 = M - e.y;
    float mx = fmaxf(en0, en1);
    #pragma unroll
    for (int off = 32; off > 0; off >>= 1) mx = fmaxf(mx, __shfl_xor(mx, off));
    const float p0 = __expf(en0 - mx), p1 = __expf(en1 - mx);
    float s = p0 + p1;
    #pragma unroll
    for (int off = 32; off > 0; off >>= 1) s += __shfl_xor(s, off);
    const float inv = 1.f / s;
    float2 o; o.x = p0*inv; o.y = p1*inv;
    *(float2*)&att[row*CI + lane*2] = o;
}

// ---------------- K4c: CAM apply: sc = g*(X att^T) + X ----------------------
__global__ __launch_bounds__(256)
void k_cam_apply(const float* __restrict__ feat2, const float* __restrict__ att,
                 const float* __restrict__ gamma, float* __restrict__ sc_feat)
{
    __shared__ float Xl[64*129];
    __shared__ __align__(16) float aT[128*64];
    const int t = threadIdx.x;
    const int pb = blockIdx.x * 64;
    const int bb = pb / HWn;
    const int ch = blockIdx.y * 64;
    for (int idx = t; idx < 64*128; idx += 256) {
        const int p = idx >> 7, ci = idx & 127;
        Xl[p*129 + ci] = feat2[(size_t)(pb + p)*CI + ci];
    }
    for (int idx = t; idx < 128*64; idx += 256) {
        const int d = idx >> 6, cc = idx & 63;
        aT[d*64 + cc] = att[((size_t)bb*CI + ch + cc)*CI + d];
    }
    __syncthreads();
    const int px = t & 63, cg = t >> 6;
    F8 accA = f8zero(), accB = f8zero();
    #pragma unroll 4
    for (int d = 0; d < 128; ++d) {
        const float xv = Xl[px*129 + d];
        const float* ap = &aT[d*64 + cg*16];
        const float4 a0 = *(const float4*)&ap[0];
        const float4 a1 = *(const float4*)&ap[4];
        const float4 a2 = *(const float4*)&ap[8];
        const float4 a3 = *(const float4*)&ap[12];
        fma8(accA, xv, a0, a1);
        fma8(accB, xv, a2, a3);
    }
    const float g = gamma[0];
    const float* fa = (const float*)&accA;
    const float* fb = (const float*)&accB;
    #pragma unroll
    for (int j = 0; j < 8; ++j) {
        const int cA = ch + cg*16 + j;
        const int cB = cA + 8;
        sc_feat[(size_t)(pb + px)*CI + cA] = g*fa[j] + Xl[px*129 + cA];
        sc_feat[(size_t)(pb + px)*CI + cB] = g*fb[j] + Xl[px*129 + cB];
    }
}

// ---------------- K6: dual 3x3 conv + BN + ReLU + sum -----------------------
__global__ __launch_bounds__(256)
void k_conv2(const float* __restrict__ inA, const float* __restrict__ inB,
             const float* __restrict__ wA, const float* __restrict__ wB,
             const float* __restrict__ g3, const float* __restrict__ b3,
             const float* __restrict__ m3, const float* __restrict__ v3,
             const float* __restrict__ g4, const float* __restrict__ b4,
             const float* __restrict__ m4, const float* __restrict__ v4,
             float* __restrict__ fsum)
{
    __shared__ float A1[34*33];
    __shared__ float A2[34*33];
    __shared__ __align__(16) float W1l[32*128];
    __shared__ __align__(16) float W2l[32*128];
    const int t = threadIdx.x;
    const int pb = blockIdx.x * 32;
    const int bb = pb / HWn, hh = (pb % HWn)/Wn, w0 = pb % Wn;
    const int px = t & 15, co = (t >> 4) * 8;
    F8 a1a = f8zero(), a1b = f8zero(), a2a = f8zero(), a2b = f8zero();

    for (int dy = 0; dy < 3; ++dy) {
        const int hy = hh + dy - 1;
        if (hy < 0 || hy >= Hn) continue;
        const size_t rbase = (size_t)(bb*Hn + hy) * Wn;
        for (int ch = 0; ch < 4; ++ch) {
            __syncthreads();
            for (int idx = t; idx < 34*32; idx += 256) {
                const int col = idx >> 5, kk = idx & 31;
                const int wx = w0 - 1 + col;
                float u = 0.f, s = 0.f;
                if (wx >= 0 && wx < Wn) {
                    const size_t gi = (rbase + wx)*CI + ch*32 + kk;
                    u = inA[gi]; s = inB[gi];
                }
                A1[col*33 + kk] = u;
                A2[col*33 + kk] = s;
            }
            for (int dx = 0; dx < 3; ++dx) {
                if (dx) __syncthreads();
                const int tap = dy*3 + dx;
                const float* w1s = wA + ((size_t)tap*CI + ch*32) * CI;
                const float* w2s = wB + ((size_t)tap*CI + ch*32) * CI;
                #pragma unroll
                for (int r = 0; r < 4; ++r) {
                    const int i4 = t + r*256;
                    const int kk = i4 >> 5, c4 = (i4 & 31) * 4;
                    *(float4*)&W1l[kk*128 + c4] = *(const float4*)&w1s[(size_t)kk*CI + c4];
                    *(float4*)&W2l[kk*128 + c4] = *(const float4*)&w2s[(size_t)kk*CI + c4];
                }
                __syncthreads();
                const float* A1r0 = &A1[(px + dx)*33];
                const float* A1r1 = &A1[(px + 16 + dx)*33];
                const float* A2r0 = &A2[(px + dx)*33];
                const float* A2r1 = &A2[(px + 16 + dx)*33];
                #pragma unroll 4
                for (int kk = 0; kk < 32; ++kk) {
                    const float x1a = A1r0[kk], x1b = A1r1[kk];
                    const float x2a = A2r0[kk], x2b = A2r1[kk];
                    const float4 u0 = *(const float4*)&W1l[kk*128 + co];
                    const float4 u1 = *(const float4*)&W1l[kk*128 + co + 4];
                    const float4 s0 = *(const float4*)&W2l[kk*128 + co];
                    const float4 s1 = *(const float4*)&W2l[kk*128 + co + 4];
                    fma8(a1a, x1a, u0, u1);
                    fma8(a1b, x1b, u0, u1);
                    fma8(a2a, x2a, s0, s1);
                    fma8(a2b, x2b, s0, s1);
                }
            }
        }
    }
    const int p0 = pb + px, p1 = p0 + 16;
    const float* f1a = (const float*)&a1a;
    const float* f1b = (const float*)&a1b;
    const float* f2a = (const float*)&a2a;
    const float* f2b = (const float*)&a2b;
    #pragma unroll
    for (int j = 0; j < 8; ++j) {
        const int c = co + j;
        const float s3 = g3[c] * rsqrtf(v3[c] + BN_EPS);
        const float s4 = g4[c] * rsqrtf(v4[c] + BN_EPS);
        const float o1a = fmaxf((f1a[j] - m3[c])*s3 + b3[c], 0.f);
        const float o1b = fmaxf((f1b[j] - m3[c])*s3 + b3[c], 0.f);
        const float o2a = fmaxf((f2a[j] - m4[c])*s4 + b4[c], 0.f);
        const float o2b = fmaxf((f2b[j] - m4[c])*s4 + b4[c], 0.f);
        fsum[(size_t)p0*CI + c] = o1a + o2a;
        fsum[(size_t)p1*CI + c] = o1b + o2b;
    }
}

// ---------------- K7: final 1x1 conv -> out ---------------------------------
__global__ __launch_bounds__(256)
void k_final(const float* __restrict__ fsum, const float* __restrict__ w8,
             float* __restrict__ out)
{
    __shared__ float Xl[64*129];
    __shared__ float w8l[128*COn];
    const int t = threadIdx.x;
    const int pb = blockIdx.x * 64;
    for (int idx = t; idx < 64*128; idx += 256) {
        const int p = idx >> 7, ci = idx & 127;
        Xl[p*129 + ci] = fsum[(size_t)(pb + p)*CI + ci];
    }
    for (int idx = t; idx < 128*COn; idx += 256) w8l[idx] = w8[idx];
    __syncthreads();
    for (int idx = t; idx < 64*COn; idx += 256) {
        const int p = idx / COn, co = idx - p*COn;
        float acc = 0.f;
        #pragma unroll 8
        for (int ci = 0; ci < 128; ++ci)
            acc = fmaf(Xl[p*129 + ci], w8l[ci*COn + co], acc);
        out[(size_t)(pb + p)*COn + co] = acc;
    }
}

extern "C" void kernel_launch(void* const* d_in, const int* in_sizes, int n_in,
                              void* d_out, int out_size, void* d_ws, size_t ws_size,
                              hipStream_t stream)
{
    const float* x    = (const float*)d_in[0];
    const float* w5a  = (const float*)d_in[1];
    const float* w5c  = (const float*)d_in[2];
    const float* wq   = (const float*)d_in[3];
    const float* bq   = (const float*)d_in[4];
    const float* wk   = (const float*)d_in[5];
    const float* bk   = (const float*)d_in[6];
    const float* wv   = (const float*)d_in[7];
    const float* bv   = (const float*)d_in[8];
    const float* pgam = (const float*)d_in[9];
    const float* cgam = (const float*)d_in[10];
    const float* w51  = (const float*)d_in[11];
    const float* w52  = (const float*)d_in[12];
    const float* w8   = (const float*)d_in[13];
    const float* bn1g = (const float*)d_in[14];
    const float* bn1b = (const float*)d_in[15];
    const float* bn1m = (const float*)d_in[16];
    const float* bn1v = (const float*)d_in[17];
    const float* bn2g = (const float*)d_in[18];
    const float* bn2b = (const float*)d_in[19];
    const float* bn2m = (const float*)d_in[20];
    const float* bn2v = (const float*)d_in[21];
    const float* bn3g = (const float*)d_in[22];
    const float* bn3b = (const float*)d_in[23];
    const float* bn3m = (const float*)d_in[24];
    const float* bn3v = (const float*)d_in[25];
    const float* bn4g = (const float*)d_in[26];
    const float* bn4b = (const float*)d_in[27];
    const float* bn4m = (const float*)d_in[28];
    const float* bn4v = (const float*)d_in[29];

    char* wsb = (char*)d_ws;
    float* feat1  = (float*)(wsb + 0);          // 8 MB (reused as fsum)
    float* feat2  = (float*)(wsb + 8388608);    // 8 MB
    float* saf    = (float*)(wsb + 16777216);   // 8 MB
    float* scf    = (float*)(wsb + 25165824);   // 8 MB
    float* energy = (float*)(wsb + 33554432);   // 256 KB
    float* att    = (float*)(wsb + 33816576);   // 256 KB
    __hip_bfloat16* qb16 = (__hip_bfloat16*)(wsb + 34078720);  // 512 KB
    __hip_bfloat16* kb16 = (__hip_bfloat16*)(wsb + 34603008);  // 512 KB
    __hip_bfloat16* vbT  = (__hip_bfloat16*)(wsb + 35127296);  // 4 MB
    float* fsum = feat1;
    float* out  = (float*)d_out;

    k_conv1<<<dim3(NPIX/32), 256, 0, stream>>>(x, w5a, w5c,
        bn1g, bn1b, bn1m, bn1v, bn2g, bn2b, bn2m, bn2v, feat1, feat2);
    k_qk<<<dim3(NPIX/64), 256, 0, stream>>>(feat1, wq, bq, wk, bk, qb16, kb16);
    k_v<<<dim3(NPIX/32), 256, 0, stream>>>(feat1, wv, bv, vbT);
    k_pam<<<dim3(NPIX/32), 64, 0, stream>>>(qb16, kb16, vbT, feat1, pgam, saf);
    k_cam_energy<<<dim3(16, Bn), 256, 0, stream>>>(feat2, energy);
    k_cam_softmax<<<dim3(Bn*CI), 64, 0, stream>>>(energy, att);
    k_cam_apply<<<dim3(NPIX/64, 2), 256, 0, stream>>>(feat2, att, cgam, scf);
    k_conv2<<<dim3(NPIX/32), 256, 0, stream>>>(saf, scf, w51, w52,
        bn3g, bn3b, bn3m, bn3v, bn4g, bn4b, bn4m, bn4v, fsum);
    k_final<<<dim3(NPIX/64), 256, 0, stream>>>(fsum, w8, out);
}

// Round 6
// 655.490 us; speedup vs baseline: 3.1542x; 1.6745x over previous
//
#include <hip/hip_runtime.h>
#include <hip/hip_bf16.h>
#include <math.h>

#define BN_EPS 1e-3f

constexpr int Bn = 4, Hn = 64, Wn = 64, CIN = 512, CI = 128;
constexpr int HWn = Hn * Wn;        // 4096
constexpr int NPIX = Bn * HWn;      // 16384
constexpr int COn = 19;

struct F8 { float4 lo, hi; };

__device__ __forceinline__ F8 f8zero() {
    F8 r; r.lo = make_float4(0.f,0.f,0.f,0.f); r.hi = make_float4(0.f,0.f,0.f,0.f); return r;
}
__device__ __forceinline__ void fma8(F8 &acc, float a, const float4 &wlo, const float4 &whi) {
    acc.lo.x = fmaf(a, wlo.x, acc.lo.x);
    acc.lo.y = fmaf(a, wlo.y, acc.lo.y);
    acc.lo.z = fmaf(a, wlo.z, acc.lo.z);
    acc.lo.w = fmaf(a, wlo.w, acc.lo.w);
    acc.hi.x = fmaf(a, whi.x, acc.hi.x);
    acc.hi.y = fmaf(a, whi.y, acc.hi.y);
    acc.hi.z = fmaf(a, whi.z, acc.hi.z);
    acc.hi.w = fmaf(a, whi.w, acc.hi.w);
}

// ---- MFMA helpers -----------------------------------------------------------
typedef __attribute__((ext_vector_type(8)))  short short8;   // 8 bf16 in 4 VGPRs
typedef __attribute__((ext_vector_type(16))) float f32x16;

__device__ __forceinline__ f32x16 f16z() {
    f32x16 z;
    #pragma unroll
    for (int i = 0; i < 16; ++i) z[i] = 0.f;
    return z;
}
// fp32 -> bf16 (RNE), pure integer ops
__device__ __forceinline__ unsigned f2b(float f) {
    union { float f; unsigned u; } c; c.f = f;
    return (c.u + 0x7FFFu + ((c.u >> 16) & 1u)) >> 16;
}
__device__ __forceinline__ unsigned pack2(float lo, float hi) {
    return (f2b(hi) << 16) | f2b(lo);
}
// split (a,b) into packed bf16 hi words + bf16 lo residuals (a in low half)
__device__ __forceinline__ void split2(float a, float b, unsigned &hi, unsigned &lo) {
    const unsigned ha = f2b(a), hb = f2b(b);
    union { unsigned u; float f; } ua, ub; ua.u = ha << 16; ub.u = hb << 16;
    hi = (hb << 16) | ha;
    lo = pack2(a - ua.f, b - ub.f);
}

// ---------------- prep: weights -> bf16 hi/lo, co-major, bank-swizzled -------
// wt1{H,L}: [32 chunk][9 tap][256 co][16 ch]  (co<128 -> w5a, else w5c)
// wt2a/b{H,L}: [8 chunk][9 tap][128 co][16 ch] for w51/w52 (294912 B each)
// within a (chunk,tap) page: byte L = co*32 + ch*2, stored at L ^ ((co&7)<<4)
__global__ __launch_bounds__(256)
void k_prep_w(const float* __restrict__ w5a, const float* __restrict__ w5c,
              const float* __restrict__ w51, const float* __restrict__ w52,
              char* __restrict__ wt1H, char* __restrict__ wt1L,
              char* __restrict__ wt2aH, char* __restrict__ wt2aL,
              char* __restrict__ wt2bH, char* __restrict__ wt2bL)
{
    int idx = blockIdx.x * 256 + threadIdx.x;
    if (idx < 589824) {                       // 32*9*256*8 pairs
        const int jp = idx & 7, co = (idx >> 3) & 255, ct = idx >> 11; // ct=c*9+tap
        const int tap = ct % 9, c = ct / 9;
        const float* src = (co < 128) ? w5a : w5c;
        const int coc = co & 127;
        const int ci = c*16 + jp*2;
        const float a = src[((size_t)tap*CIN + ci)*CI + coc];
        const float b = src[((size_t)tap*CIN + ci + 1)*CI + coc];
        unsigned hi, lo; split2(a, b, hi, lo);
        const int L = (co*32 + jp*4) ^ ((co & 7) << 4);
        *(unsigned*)(wt1H + (size_t)ct*8192 + L) = hi;
        *(unsigned*)(wt1L + (size_t)ct*8192 + L) = lo;
    } else {
        int k = idx - 589824;                 // 2 * 8*9*128*8 pairs
        if (k >= 147456) return;
        const float* src = (k < 73728) ? w51 : w52;
        char* dstH = (k < 73728) ? wt2aH : wt2bH;
        char* dstL = (k < 73728) ? wt2aL : wt2bL;
        if (k >= 73728) k -= 73728;
        const int jp = k & 7, co = (k >> 3) & 127, ct = k >> 10; // ct=c*9+tap
        const int tap = ct % 9, c = ct / 9;
        const int ci = c*16 + jp*2;
        const float a = src[((size_t)tap*CI + ci)*CI + co];
        const float b = src[((size_t)tap*CI + ci + 1)*CI + co];
        unsigned hi, lo; split2(a, b, hi, lo);
        const int L = (co*32 + jp*4) ^ ((co & 7) << 4);
        *(unsigned*)(dstH + (size_t)ct*4096 + L) = hi;
        *(unsigned*)(dstL + (size_t)ct*4096 + L) = lo;
    }
}

// ---------------- prep: BN -> folded scale/bias tables -----------------------
__global__ __launch_bounds__(256)
void k_prep_bn(const float* g1, const float* b1, const float* m1, const float* v1,
               const float* g2, const float* b2, const float* m2, const float* v2,
               const float* g3, const float* b3, const float* m3, const float* v3,
               const float* g4, const float* b4, const float* m4, const float* v4,
               float* bnAs, float* bnAb, float* bnBs, float* bnBb)
{
    const int t = threadIdx.x, c = t & 127;
    {
        const float *g = (t < 128) ? g1 : g2, *b = (t < 128) ? b1 : b2;
        const float *m = (t < 128) ? m1 : m2, *v = (t < 128) ? v1 : v2;
        const float s = g[c] * rsqrtf(v[c] + BN_EPS);
        bnAs[t] = s; bnAb[t] = b[c] - m[c]*s;
    }
    {
        const float *g = (t < 128) ? g3 : g4, *b = (t < 128) ? b3 : b4;
        const float *m = (t < 128) ? m3 : m4, *v = (t < 128) ? v3 : v4;
        const float s = g[c] * rsqrtf(v[c] + BN_EPS);
        bnBs[t] = s; bnBb[t] = b[c] - m[c]*s;
    }
}

// ---------------- MFMA 3x3 conv, bf16x3 split + folded BN + ReLU -------------
// Block = one image row (64 px), 256 thr / 4 waves. Wave = 2 M-tiles x NTPW
// N-tiles (32x32 each). K chunked by 16 ch; W restaged per-dy (3 taps) in
// hi+lo planes; X staged per-chunk as hi+lo with XOR swizzle ((slot&7)<<4),
// zeroed halo slots. 3-term product: xh*wh + xl*wh + xh*wl (~fp32 accurate).
// mfma(A=W^T[co][k], B=X[px][k]) -> D[col=px][row=co]  (k_pam-validated map)
template<int CICH, bool DUAL>
__global__ __launch_bounds__(256)
void k_convm(const float* __restrict__ xin,
             const char* __restrict__ wtH, const char* __restrict__ wtL,
             const float* __restrict__ bnS, const float* __restrict__ bnBi,
             float* __restrict__ out0, float* __restrict__ out1)
{
    constexpr int NCO    = DUAL ? 256 : 128;
    constexpr int NCHNK  = CICH / 16;
    constexpr int WPAGE  = NCO * 32;          // bytes per tap page
    constexpr int WSTG   = 3 * WPAGE;         // 3 taps staged at a time
    constexpr int XPAGE  = 66 * 32;           // 2112 B per staged row
    constexpr int NTPW   = NCO / 128;         // N-tiles per wave (2 or 1)
    __shared__ __align__(16) char smem[2*WSTG + 6*XPAGE];
    char* Wh = smem;
    char* Wl = smem + WSTG;
    char* Xh = smem + 2*WSTG;
    char* Xl = Xh + 3*XPAGE;

    const int t   = threadIdx.x;
    const int row = blockIdx.x;               // 0..255 = b*64 + h
    const int bb  = row >> 6, hh = row & 63;
    const int dyLo = (hh == 0)  ? 1 : 0;
    const int dyHi = (hh == 63) ? 1 : 2;
    const int l = t & 63, w = t >> 6;
    const int lo5 = l & 31, hf = l >> 5;

    f32x16 acc[2][NTPW];
    #pragma unroll
    for (int mi = 0; mi < 2; ++mi)
        #pragma unroll
        for (int nj = 0; nj < NTPW; ++nj) acc[mi][nj] = f16z();

    for (int c = 0; c < NCHNK; ++c) {
        bool xst = false;
        for (int dy = 0; dy < 3; ++dy) {
            if (dy < dyLo || dy > dyHi) continue;     // block-uniform
            __syncthreads();                           // prev compute done
            if (!xst) {
                // stage X hi/lo: valid rows x 66 slots x 16 ch
                for (int u = t; u < 792; u += 256) {   // 3*66*4 8B-units
                    const int dyr = u / 264, rs = u - dyr*264;
                    const int s = rs >> 2, u4 = rs & 3;
                    if (dyr < dyLo || dyr > dyHi) continue;
                    uint2 vh; vh.x = 0u; vh.y = 0u;
                    uint2 vl; vl.x = 0u; vl.y = 0u;
                    if (s >= 1 && s <= 64) {
                        const float4 v4 = *(const float4*)&xin[
                            (((size_t)bb*Hn + (hh + dyr - 1))*Wn + (s - 1))*CICH + c*16 + u4*4];
                        split2(v4.x, v4.y, vh.x, vl.x);
                        split2(v4.z, v4.w, vh.y, vl.y);
                    }
                    const int off = dyr*XPAGE + ((s*32 + u4*8) ^ ((s & 7) << 4));
                    *(uint2*)(Xh + off) = vh;
                    *(uint2*)(Xl + off) = vl;
                }
                xst = true;
            }
            // stage W (this chunk, taps dy*3..dy*3+2), hi+lo
            {
                constexpr int NU = WSTG / 16 / 256;    // 6 (DUAL) or 3
                const float4* sH = (const float4*)(wtH + (size_t)(c*9 + dy*3)*WPAGE);
                const float4* sL = (const float4*)(wtL + (size_t)(c*9 + dy*3)*WPAGE);
                float4* dH = (float4*)Wh;
                float4* dL = (float4*)Wl;
                #pragma unroll
                for (int i = 0; i < NU; ++i) {
                    dH[t + i*256] = sH[t + i*256];
                    dL[t + i*256] = sL[t + i*256];
                }
            }
            __syncthreads();
            // compute 3 taps of this dy
            const char* Xph = Xh + dy*XPAGE;
            const char* Xpl = Xl + dy*XPAGE;
            #pragma unroll
            for (int dx = 0; dx < 3; ++dx) {
                short8 xfh[2], xfl[2], wfh[NTPW], wfl[NTPW];
                #pragma unroll
                for (int mi = 0; mi < 2; ++mi) {
                    const int s = mi*32 + lo5 + dx;
                    const int xo = (s*32 + hf*16) ^ ((s & 7) << 4);
                    xfh[mi] = *(const short8*)(Xph + xo);
                    xfl[mi] = *(const short8*)(Xpl + xo);
                }
                #pragma unroll
                for (int nj = 0; nj < NTPW; ++nj) {
                    const int cr = (w*NTPW + nj)*32 + lo5;
                    const int wo = dx*WPAGE + ((cr*32 + hf*16) ^ ((lo5 & 7) << 4));
                    wfh[nj] = *(const short8*)(Wh + wo);
                    wfl[nj] = *(const short8*)(Wl + wo);
                }
                #pragma unroll
                for (int mi = 0; mi < 2; ++mi)
                    #pragma unroll
                    for (int nj = 0; nj < NTPW; ++nj) {
                        acc[mi][nj] = __builtin_amdgcn_mfma_f32_32x32x16_bf16(
                            wfh[nj], xfh[mi], acc[mi][nj], 0, 0, 0);
                        acc[mi][nj] = __builtin_amdgcn_mfma_f32_32x32x16_bf16(
                            wfh[nj], xfl[mi], acc[mi][nj], 0, 0, 0);
                        acc[mi][nj] = __builtin_amdgcn_mfma_f32_32x32x16_bf16(
                            wfl[nj], xfh[mi], acc[mi][nj], 0, 0, 0);
                    }
            }
        }
    }
    // ---- epilogue: folded BN + ReLU, scatter store ----
    #pragma unroll
    for (int mi = 0; mi < 2; ++mi) {
        const int px = mi*32 + lo5;
        const size_t p = (size_t)row*Wn + px;
        #pragma unroll
        for (int nj = 0; nj < NTPW; ++nj) {
            #pragma unroll
            for (int r = 0; r < 16; ++r) {
                const int co_full = (w*NTPW + nj)*32 + (r & 3) + 8*(r >> 2) + 4*hf;
                const float val = fmaxf(fmaf(acc[mi][nj][r], bnS[co_full], bnBi[co_full]), 0.f);
                if constexpr (DUAL) {
                    float* dst = (co_full < 128) ? out0 : out1;
                    dst[p*CI + (co_full & 127)] = val;
                } else {
                    out0[p*CI + co_full] = val;
                }
            }
        }
    }
}

// ---------------- K2a: q,k 1x1 conv -> bf16 [NPIX][16] each ------------------
__global__ __launch_bounds__(256)
void k_qk(const float* __restrict__ feat1,
          const float* __restrict__ wq, const float* __restrict__ bq,
          const float* __restrict__ wk, const float* __restrict__ bk,
          __hip_bfloat16* __restrict__ qb, __hip_bfloat16* __restrict__ kb)
{
    __shared__ float Al[64*129];
    __shared__ __align__(16) float Wl[128*32];
    const int t = threadIdx.x;
    const int pb = blockIdx.x * 64;
    for (int idx = t; idx < 64*128; idx += 256) {
        const int p = idx >> 7, ci = idx & 127;
        Al[p*129 + ci] = feat1[(size_t)(pb + p)*CI + ci];
    }
    for (int idx = t; idx < 128*32; idx += 256) {
        const int ci = idx >> 5, c = idx & 31;
        Wl[idx] = (c < 16) ? wq[ci*16 + c] : wk[ci*16 + (c - 16)];
    }
    __syncthreads();
    const int p = t & 63, cg = t >> 6, co = cg * 8;
    F8 acc = f8zero();
    #pragma unroll 8
    for (int ci = 0; ci < 128; ++ci) {
        const float a = Al[p*129 + ci];
        const float4 wlo = *(const float4*)&Wl[ci*32 + co];
        const float4 whi = *(const float4*)&Wl[ci*32 + co + 4];
        fma8(acc, a, wlo, whi);
    }
    const float* af = (const float*)&acc;
    #pragma unroll
    for (int j = 0; j < 8; ++j) {
        const int c = co + j;
        if (c < 16) qb[(size_t)(pb + p)*16 + c]        = __float2bfloat16(af[j] + bq[c]);
        else        kb[(size_t)(pb + p)*16 + (c - 16)] = __float2bfloat16(af[j] + bk[c - 16]);
    }
}

// ---------------- K2b: v 1x1 conv -> bf16 TRANSPOSED [b][c][pix] -------------
__global__ __launch_bounds__(256)
void k_v(const float* __restrict__ feat1, const float* __restrict__ wv,
         const float* __restrict__ bv, __hip_bfloat16* __restrict__ vbT)
{
    __shared__ float Al[32*129];
    __shared__ __align__(16) float Wl[64*128];
    const int t = threadIdx.x;
    const int pb = blockIdx.x * 32;
    for (int idx = t; idx < 32*128; idx += 256) {
        const int p = idx >> 7, ci = idx & 127;
        Al[p*129 + ci] = feat1[(size_t)(pb + p)*CI + ci];
    }
    const int px = t & 15, co = (t >> 4) * 8;
    F8 acc0 = f8zero(), acc1 = f8zero();
    for (int ch = 0; ch < 2; ++ch) {
        __syncthreads();
        #pragma unroll
        for (int r = 0; r < 8; ++r) {
            const int i4 = t + r*256;
            const int kk = i4 >> 5, c4 = (i4 & 31) * 4;
            *(float4*)&Wl[kk*128 + c4] = *(const float4*)&wv[(size_t)(ch*64 + kk)*CI + c4];
        }
        __syncthreads();
        #pragma unroll 4
        for (int kk = 0; kk < 64; ++kk) {
            const float a0 = Al[px*129 + ch*64 + kk];
            const float a1 = Al[(px+16)*129 + ch*64 + kk];
            const float4 wlo = *(const float4*)&Wl[kk*128 + co];
            const float4 whi = *(const float4*)&Wl[kk*128 + co + 4];
            fma8(acc0, a0, wlo, whi);
            fma8(acc1, a1, wlo, whi);
        }
    }
    const int p0 = pb + px;
    const int bb = p0 / HWn, pin0 = p0 % HWn;
    const float* a0f = (const float*)&acc0;
    const float* a1f = (const float*)&acc1;
    #pragma unroll
    for (int j = 0; j < 8; ++j) {
        const int c = co + j;
        const size_t rowb = ((size_t)bb*CI + c) * HWn;
        vbT[rowb + pin0]      = __float2bfloat16(a0f[j] + bv[c]);
        vbT[rowb + pin0 + 16] = __float2bfloat16(a1f[j] + bv[c]);
    }
}

// ---------------- K3: PAM flash attention via MFMA ---------------------------
__global__ __launch_bounds__(64)
void k_pam(const __hip_bfloat16* __restrict__ qb, const __hip_bfloat16* __restrict__ kb,
           const __hip_bfloat16* __restrict__ vbT, const float* __restrict__ feat1,
           const float* __restrict__ gamma, float* __restrict__ saf)
{
    __shared__ unsigned Ppk[32*32];   // [key-pair 0..31][q 0..31], bf16x2 packed
    const int l   = threadIdx.x;
    const int lo5 = l & 31, h = l >> 5;
    const int q0  = blockIdx.x * 32;
    const int bb  = q0 / HWn;
    const size_t jb = (size_t)bb * HWn;
    const __hip_bfloat16* vbB = vbT + (size_t)bb * CI * HWn;

    const short8 qfrag = *(const short8*)&qb[(size_t)(q0 + lo5)*16 + 8*h];
    const f32x16 zro = f16z();

    f32x16 o[4];
    #pragma unroll
    for (int cb = 0; cb < 4; ++cb) o[cb] = f16z();

    float m_run = -1e30f, s_run = 0.f;

    for (int k0 = 0; k0 < HWn; k0 += 64) {
        const short8 kf0 = *(const short8*)&kb[(jb + k0 +      lo5)*16 + 8*h];
        const short8 kf1 = *(const short8*)&kb[(jb + k0 + 32 + lo5)*16 + 8*h];
        short8 vf[4][4];
        #pragma unroll
        for (int s = 0; s < 4; ++s)
            #pragma unroll
            for (int cb = 0; cb < 4; ++cb)
                vf[s][cb] = *(const short8*)&vbB[((size_t)(cb*32 + lo5))*HWn + k0 + s*16 + 8*h];

        f32x16 e0 = __builtin_amdgcn_mfma_f32_32x32x16_bf16(kf0, qfrag, zro, 0, 0, 0);
        f32x16 e1 = __builtin_amdgcn_mfma_f32_32x32x16_bf16(kf1, qfrag, zro, 0, 0, 0);

        float mt = fmaxf(e0[0], e1[0]);
        #pragma unroll
        for (int r = 1; r < 16; ++r) mt = fmaxf(mt, fmaxf(e0[r], e1[r]));
        mt = fmaxf(mt, __shfl_xor(mt, 32));

        if (__any(mt > m_run + 8.f)) {
            const float mnew = fmaxf(m_run, mt);
            const float sc = __expf(m_run - mnew);
            s_run *= sc;
            #pragma unroll
            for (int cb = 0; cb < 4; ++cb)
                #pragma unroll
                for (int r = 0; r < 16; ++r) o[cb][r] *= sc;
            m_run = mnew;
        }

        #pragma unroll
        for (int r = 0; r < 16; ++r) {
            e0[r] = __expf(e0[r] - m_run);
            e1[r] = __expf(e1[r] - m_run);
        }
        float ss = 0.f;
        #pragma unroll
        for (int r = 0; r < 16; ++r) ss += e0[r] + e1[r];
        s_run += ss;

        #pragma unroll
        for (int r = 0; r < 16; r += 2) {
            const int pidx = ((r & 3) >> 1) + 4*(r >> 2) + 2*h;
            Ppk[pidx*32 + lo5]        = pack2(e0[r], e0[r+1]);
            Ppk[(16 + pidx)*32 + lo5] = pack2(e1[r], e1[r+1]);
        }
        #pragma unroll
        for (int s = 0; s < 4; ++s) {
            union { unsigned u[4]; short8 s8; } P;
            #pragma unroll
            for (int w = 0; w < 4; ++w)
                P.u[w] = Ppk[(s*8 + 4*h + w)*32 + lo5];
            #pragma unroll
            for (int cb = 0; cb < 4; ++cb)
                o[cb] = __builtin_amdgcn_mfma_f32_32x32x16_bf16(vf[s][cb], P.s8, o[cb], 0, 0, 0);
        }
    }

    const float s_tot = s_run + __shfl_xor(s_run, 32);
    const float inv = 1.f / s_tot;
    const float g = gamma[0];
    const size_t q = (size_t)q0 + lo5;
    #pragma unroll
    for (int cb = 0; cb < 4; ++cb)
        #pragma unroll
        for (int r = 0; r < 16; ++r) {
            const int c = cb*32 + (r & 3) + 8*(r >> 2) + 4*h;
            const size_t idx = q*CI + c;
            saf[idx] = g*(o[cb][r]*inv) + feat1[idx];
        }
}

// ---------------- K4a: CAM energy = X^T X (per batch, 32x32 tiles) ----------
__global__ __launch_bounds__(256)
void k_cam_energy(const float* __restrict__ feat2, float* __restrict__ energy)
{
    __shared__ float Xc[64*33];
    __shared__ float Xd[64*33];
    const int t = threadIdx.x;
    const int tile = blockIdx.x;            // 0..15
    const int bb = blockIdx.y;
    const int c0 = (tile & 3) * 32, d0 = (tile >> 2) * 32;
    const int tc = t & 31, dg = t >> 5;
    float acc[4] = {0.f,0.f,0.f,0.f};
    const size_t base = (size_t)bb * HWn;
    for (int n0 = 0; n0 < HWn; n0 += 64) {
        __syncthreads();
        for (int idx = t; idx < 64*32; idx += 256) {
            const int n = idx >> 5, col = idx & 31;
            Xc[n*33 + col] = feat2[(base + n0 + n)*CI + c0 + col];
            Xd[n*33 + col] = feat2[(base + n0 + n)*CI + d0 + col];
        }
        __syncthreads();
        #pragma unroll 4
        for (int n = 0; n < 64; ++n) {
            const float a = Xc[n*33 + tc];
            #pragma unroll
            for (int i = 0; i < 4; ++i)
                acc[i] = fmaf(a, Xd[n*33 + dg*4 + i], acc[i]);
        }
    }
    const int c = c0 + tc;
    #pragma unroll
    for (int i = 0; i < 4; ++i)
        energy[((size_t)bb*CI + c)*CI + d0 + dg*4 + i] = acc[i];
}

// ---------------- K4b: CAM softmax (max-subtract variant, per row) ----------
__global__ __launch_bounds__(64)
void k_cam_softmax(const float* __restrict__ energy, float* __restrict__ att)
{
    const int lane = threadIdx.x;
    const size_t row = blockIdx.x;
    const float2 e = *(const float2*)&energy[row*CI + lane*2];
    float M = fmaxf(e.x, e.y);
    #pragma unroll
    for (int off = 32; off > 0; off >>= 1) M = fmaxf(M, __shfl_xor(M, off));
    const float en0 = M - e.x, en1 = M - e.y;
    float mx = fmaxf(en0, en1);
    #pragma unroll
    for (int off = 32; off > 0; off >>= 1) mx = fmaxf(mx, __shfl_xor(mx, off));
    const float p0 = __expf(en0 - mx), p1 = __expf(en1 - mx);
    float s = p0 + p1;
    #pragma unroll
    for (int off = 32; off > 0; off >>= 1) s += __shfl_xor(s, off);
    const float inv = 1.f / s;
    float2 o; o.x = p0*inv; o.y = p1*inv;
    *(float2*)&att[row*CI + lane*2] = o;
}

// ---------------- K4c: CAM apply: sc = g*(X att^T) + X ----------------------
__global__ __launch_bounds__(256)
void k_cam_apply(const float* __restrict__ feat2, const float* __restrict__ att,
                 const float* __restrict__ gamma, float* __restrict__ sc_feat)
{
    __shared__ float Xl[64*129];
    __shared__ __align__(16) float aT[128*64];
    const int t = threadIdx.x;
    const int pb = blockIdx.x * 64;
    const int bb = pb / HWn;
    const int ch = blockIdx.y * 64;
    for (int idx = t; idx < 64*128; idx += 256) {
        const int p = idx >> 7, ci = idx & 127;
        Xl[p*129 + ci] = feat2[(size_t)(pb + p)*CI + ci];
    }
    for (int idx = t; idx < 128*64; idx += 256) {
        const int d = idx >> 6, cc = idx & 63;
        aT[d*64 + cc] = att[((size_t)bb*CI + ch + cc)*CI + d];
    }
    __syncthreads();
    const int px = t & 63, cg = t >> 6;
    F8 accA = f8zero(), accB = f8zero();
    #pragma unroll 4
    for (int d = 0; d < 128; ++d) {
        const float xv = Xl[px*129 + d];
        const float* ap = &aT[d*64 + cg*16];
        const float4 a0 = *(const float4*)&ap[0];
        const float4 a1 = *(const float4*)&ap[4];
        const float4 a2 = *(const float4*)&ap[8];
        const float4 a3 = *(const float4*)&ap[12];
        fma8(accA, xv, a0, a1);
        fma8(accB, xv, a2, a3);
    }
    const float g = gamma[0];
    const float* fa = (const float*)&accA;
    const float* fb = (const float*)&accB;
    #pragma unroll
    for (int j = 0; j < 8; ++j) {
        const int cA = ch + cg*16 + j;
        const int cB = cA + 8;
        sc_feat[(size_t)(pb + px)*CI + cA] = g*fa[j] + Xl[px*129 + cA];
        sc_feat[(size_t)(pb + px)*CI + cB] = g*fb[j] + Xl[px*129 + cB];
    }
}

// ---------------- K7: final 1x1 conv (sum of two branches) -> out ------------
__global__ __launch_bounds__(256)
void k_final(const float* __restrict__ sa, const float* __restrict__ sc,
             const float* __restrict__ w8, float* __restrict__ out)
{
    __shared__ float Xl[64*129];
    __shared__ float w8l[128*COn];
    const int t = threadIdx.x;
    const int pb = blockIdx.x * 64;
    for (int idx = t; idx < 64*128; idx += 256) {
        const int p = idx >> 7, ci = idx & 127;
        const size_t gi = (size_t)(pb + p)*CI + ci;
        Xl[p*129 + ci] = sa[gi] + sc[gi];
    }
    for (int idx = t; idx < 128*COn; idx += 256) w8l[idx] = w8[idx];
    __syncthreads();
    for (int idx = t; idx < 64*COn; idx += 256) {
        const int p = idx / COn, co = idx - p*COn;
        float acc = 0.f;
        #pragma unroll 8
        for (int ci = 0; ci < 128; ++ci)
            acc = fmaf(Xl[p*129 + ci], w8l[ci*COn + co], acc);
        out[(size_t)(pb + p)*COn + co] = acc;
    }
}

extern "C" void kernel_launch(void* const* d_in, const int* in_sizes, int n_in,
                              void* d_out, int out_size, void* d_ws, size_t ws_size,
                              hipStream_t stream)
{
    const float* x    = (const float*)d_in[0];
    const float* w5a  = (const float*)d_in[1];
    const float* w5c  = (const float*)d_in[2];
    const float* wq   = (const float*)d_in[3];
    const float* bq   = (const float*)d_in[4];
    const float* wk   = (const float*)d_in[5];
    const float* bk   = (const float*)d_in[6];
    const float* wv   = (const float*)d_in[7];
    const float* bv   = (const float*)d_in[8];
    const float* pgam = (const float*)d_in[9];
    const float* cgam = (const float*)d_in[10];
    const float* w51  = (const float*)d_in[11];
    const float* w52  = (const float*)d_in[12];
    const float* w8   = (const float*)d_in[13];
    const float* bn1g = (const float*)d_in[14];
    const float* bn1b = (const float*)d_in[15];
    const float* bn1m = (const float*)d_in[16];
    const float* bn1v = (const float*)d_in[17];
    const float* bn2g = (const float*)d_in[18];
    const float* bn2b = (const float*)d_in[19];
    const float* bn2m = (const float*)d_in[20];
    const float* bn2v = (const float*)d_in[21];
    const float* bn3g = (const float*)d_in[22];
    const float* bn3b = (const float*)d_in[23];
    const float* bn3m = (const float*)d_in[24];
    const float* bn3v = (const float*)d_in[25];
    const float* bn4g = (const float*)d_in[26];
    const float* bn4b = (const float*)d_in[27];
    const float* bn4m = (const float*)d_in[28];
    const float* bn4v = (const float*)d_in[29];

    char* wsb = (char*)d_ws;
    float* feat1  = (float*)(wsb + 0);          // 8 MB (reused as sa_conv)
    float* feat2  = (float*)(wsb + 8388608);    // 8 MB (reused as sc_conv)
    float* saf    = (float*)(wsb + 16777216);   // 8 MB
    float* scf    = (float*)(wsb + 25165824);   // 8 MB
    float* energy = (float*)(wsb + 33554432);   // 256 KB
    float* att    = (float*)(wsb + 33816576);   // 256 KB
    __hip_bfloat16* qb16 = (__hip_bfloat16*)(wsb + 34078720);  // 512 KB
    __hip_bfloat16* kb16 = (__hip_bfloat16*)(wsb + 34603008);  // 512 KB
    __hip_bfloat16* vbT  = (__hip_bfloat16*)(wsb + 35127296);  // 4 MB -> 39321600
    char* wt1H = wsb + 25165824;                // alias scf (dead until cam_apply)
    char* wt1L = wsb + 27525120;                // 2359296 each -> 29884416 (< scf end)
    char* wt2aH = wsb + 39321600;               // 294912 -> 39616512
    char* wt2aL = wsb + 39616512;               // 294912 -> 39911424
    char* wt2bH = wsb + 39911424;               // 294912 -> 40206336
    char* wt2bL = wsb + 40206336;               // 294912 -> 40501248
    float* bnAs = (float*)(wsb + 40501248);     // 1 KB each
    float* bnAb = (float*)(wsb + 40502272);
    float* bnBs = (float*)(wsb + 40503296);
    float* bnBb = (float*)(wsb + 40504320);     // high-water 40505344
    float* sa_conv = feat1;                     // alias: feat1 dead after k_pam
    float* sc_conv = feat2;                     // alias: feat2 dead after cam_apply
    float* out  = (float*)d_out;

    k_prep_w<<<dim3(2880), 256, 0, stream>>>(w5a, w5c, w51, w52,
        wt1H, wt1L, wt2aH, wt2aL, wt2bH, wt2bL);
    k_prep_bn<<<dim3(1), 256, 0, stream>>>(bn1g, bn1b, bn1m, bn1v, bn2g, bn2b, bn2m, bn2v,
                                           bn3g, bn3b, bn3m, bn3v, bn4g, bn4b, bn4m, bn4v,
                                           bnAs, bnAb, bnBs, bnBb);
    k_convm<512, true><<<dim3(256), 256, 0, stream>>>(x, wt1H, wt1L, bnAs, bnAb, feat1, feat2);
    k_qk<<<dim3(NPIX/64), 256, 0, stream>>>(feat1, wq, bq, wk, bk, qb16, kb16);
    k_v<<<dim3(NPIX/32), 256, 0, stream>>>(feat1, wv, bv, vbT);
    k_pam<<<dim3(NPIX/32), 64, 0, stream>>>(qb16, kb16, vbT, feat1, pgam, saf);
    k_cam_energy<<<dim3(16, Bn), 256, 0, stream>>>(feat2, energy);
    k_cam_softmax<<<dim3(Bn*CI), 64, 0, stream>>>(energy, att);
    k_cam_apply<<<dim3(NPIX/64, 2), 256, 0, stream>>>(feat2, att, cgam, scf);
    k_convm<128, false><<<dim3(256), 256, 0, stream>>>(saf, wt2aH, wt2aL, bnBs,       bnBb,       sa_conv, nullptr);
    k_convm<128, false><<<dim3(256), 256, 0, stream>>>(scf, wt2bH, wt2bL, bnBs + 128, bnBb + 128, sc_conv, nullptr);
    k_final<<<dim3(NPIX/64), 256, 0, stream>>>(sa_conv, sc_conv, w8, out);
}